// Round 1
// 231.349 us; speedup vs baseline: 1.0081x; 1.0081x over previous
//
#include <hip/hip_runtime.h>
#include <hip/hip_bf16.h>
#include <stdint.h>

using bf16 = __hip_bfloat16;
typedef __attribute__((ext_vector_type(8))) short short8;
typedef __attribute__((ext_vector_type(4))) float floatx4;

#define DD 32
#define DL3 32768      // 32^3
#define BATCH 256
#define NK 1024        // 32*32

// async global->LDS, 16B per lane (wave-uniform base + lane*16 layout respected)
__device__ __forceinline__ void load16(const void* g, void* l) {
  __builtin_amdgcn_global_load_lds((const __attribute__((address_space(1))) void*)g,
                                   (__attribute__((address_space(3))) void*)l,
                                   16, 0, 0);
}

// dst[b][v][f][u] = x[b][u][v][f]  (fp32 -> bf16), so GEMM step 0 uses the same
// A-gather pattern as steps 1..5:  A[(b,f)][(v*32+u)] = src[b,v,f,u]
__global__ __launch_bounds__(256) void prep_x(const float* __restrict__ x, bf16* __restrict__ dst) {
  int b = blockIdx.x >> 5, v = blockIdx.x & 31;
  __shared__ float tile[32][33];
  const float* xb = x + (size_t)b * DL3 + v * DD;
  int t = threadIdx.x;
#pragma unroll
  for (int it = 0; it < 4; ++it) {
    int u = (t >> 5) + it * 8, f = t & 31;
    tile[u][f] = xb[u * NK + f];               // coalesced 128B per 32 lanes
  }
  __syncthreads();
  bf16* db = dst + (size_t)b * DL3 + v * NK;
#pragma unroll
  for (int it = 0; it < 4; ++it) {
    int f = (t >> 5) + it * 8, u = t & 31;
    db[f * DD + u] = __float2bfloat16(tile[u][f]);  // contiguous bf16 writes
  }
}

// nodeT[i][n][v*32+u] = node[i][u*32+v][n]  (fp32 -> bf16)
__global__ __launch_bounds__(256) void prep_nodes(const float* __restrict__ nodes, bf16* __restrict__ dst) {
  int id = blockIdx.x;
  int nb = id & 31, kb = (id >> 5) & 31, i = id >> 10;
  const float* src = nodes + (size_t)i * 1048576;
  bf16* d = dst + (size_t)i * 1048576;
  __shared__ float tile[32][33];
  int t = threadIdx.x;
#pragma unroll
  for (int it = 0; it < 4; ++it) {
    int u = (t >> 5) + it * 8, j = t & 31;
    tile[u][j] = src[(size_t)(u * 32 + kb) * 1024 + nb * 32 + j];
  }
  __syncthreads();
#pragma unroll
  for (int it = 0; it < 4; ++it) {
    int j = (t >> 5) + it * 8, u = t & 31;
    d[(size_t)(nb * 32 + j) * 1024 + kb * 32 + u] = __float2bfloat16(tile[u][j]);
  }
}

// One contraction step as GEMM: C[(b*32+f)][n] = sum_k A[(b,f)][k] * Bt[k][n]
//   A[(b,f)][(v*32+u)] = Asrc[b*32768 + v*1024 + f*32 + u]   (k-contiguous runs of 32)
//   Bt[k][n] = nodeT[n][k]
// Tile 128x128, BK=64, DOUBLE-BUFFERED (2-phase): issue next tile's
// global_load_lds into buf^1, compute on buf, single __syncthreads per tile
// (its vmcnt(0)+lgkmcnt(0) drain is the pipeline wait). LDS 64KB -> 2 blocks/CU
// (grid is 512 = 2/CU anyway).
template <bool FINAL>
__global__ __launch_bounds__(256) void entangler_gemm(
    const bf16* __restrict__ A, const bf16* __restrict__ Bn,
    bf16* __restrict__ Cb, float* __restrict__ Cf, const float* __restrict__ bias) {
  __shared__ bf16 sA[2][8192];   // [buf][vv*4096 + m*32 + u] : m=(bb*32+f)
  __shared__ bf16 sB[2][8192];   // [buf][vv*4096 + n*32 + u]
  const int t = threadIdx.x;
  const int lane = t & 63;
  const int lane16 = lane & 15, quad = lane >> 4;
  const int w = t >> 6;
  const int m0 = (w >> 1) * 64, n0 = (w & 1) * 64;
  const int b0 = blockIdx.x * 4;          // 4 batch elements per M-tile of 128
  const int N0 = blockIdx.y * 128;

  floatx4 acc[4][4];
#pragma unroll
  for (int i = 0; i < 4; ++i)
#pragma unroll
    for (int j = 0; j < 4; ++j)
      acc[i][j] = (floatx4){0.f, 0.f, 0.f, 0.f};

  const bf16* Ab = A + (size_t)b0 * DL3;
  const bf16* Bb = Bn + (size_t)N0 * NK;

  // Per-thread staging pointers for K-tile 0; advanced by one K-tile (2 v-chunks)
  // after each stage. e = flat bf16 element index into the 8192-element buffer.
  const bf16* gA[4];
  const bf16* gB[4];
  int eoff[4];
#pragma unroll
  for (int r = 0; r < 4; ++r) {
    int e = (r * 256 + t) * 8;            // byte offset = e*2 = lane*16 within wave ✓
    eoff[r] = e;
    int vv = e >> 12;                     // 0..1 sub-chunk (v within tile)
    int bb = (e >> 10) & 3;               // batch element within M-tile
    int remA = e & 1023;                  // f*32+u
    gA[r] = Ab + (size_t)bb * DL3 + vv * NK + remA;
    int n = (e >> 5) & 127;
    int u8 = e & 31;
    gB[r] = Bb + (size_t)n * NK + vv * 32 + u8;
  }

  // Prologue: stage K-tile 0 into buf 0.
#pragma unroll
  for (int r = 0; r < 4; ++r) { load16(gA[r], &sA[0][eoff[r]]); gA[r] += 2 * NK; }
#pragma unroll
  for (int r = 0; r < 4; ++r) { load16(gB[r], &sB[0][eoff[r]]); gB[r] += 2 * 32; }
  __syncthreads();   // vmcnt(0) drain for tile 0

#pragma unroll
  for (int kt = 0; kt < 16; ++kt) {
    const int buf = kt & 1;
    // Phase 1: issue next K-tile's loads into the other buffer (stays in flight
    // across the compute phase; drained by the __syncthreads below).
    if (kt < 15) {
#pragma unroll
      for (int r = 0; r < 4; ++r) { load16(gA[r], &sA[buf ^ 1][eoff[r]]); gA[r] += 2 * NK; }
#pragma unroll
      for (int r = 0; r < 4; ++r) { load16(gB[r], &sB[buf ^ 1][eoff[r]]); gB[r] += 2 * 32; }
    }
    // Phase 2: compute on current buffer (2 k-chunks of 32).
#pragma unroll
    for (int kk = 0; kk < 2; ++kk) {
      const bf16* pA = &sA[buf][kk * 4096];
      const bf16* pB = &sB[buf][kk * 4096];
      short8 af[4], bfr[4];
#pragma unroll
      for (int i = 0; i < 4; ++i)
        af[i] = *(const short8*)(pA + (m0 + i * 16 + lane16) * 32 + quad * 8);
#pragma unroll
      for (int j = 0; j < 4; ++j)
        bfr[j] = *(const short8*)(pB + (n0 + j * 16 + lane16) * 32 + quad * 8);
#pragma unroll
      for (int i = 0; i < 4; ++i)
#pragma unroll
        for (int j = 0; j < 4; ++j)
          acc[i][j] = __builtin_amdgcn_mfma_f32_16x16x32_bf16(af[i], bfr[j], acc[i][j], 0, 0, 0);
    }
    // Single barrier per tile: drains the prefetch (vmcnt) AND publishes that
    // all waves finished reading buf (safe to overwrite next iteration).
    if (kt < 15) __syncthreads();
  }

  // Epilogue. C/D layout: col = lane&15, row = quad*4 + reg  [m89-verified]
  const int R0 = blockIdx.x * 128;
#pragma unroll
  for (int i = 0; i < 4; ++i) {
#pragma unroll
    for (int j = 0; j < 4; ++j) {
#pragma unroll
      for (int r = 0; r < 4; ++r) {
        int row = R0 + m0 + i * 16 + quad * 4 + r;
        int col = N0 + n0 + j * 16 + lane16;
        if (FINAL) {
          float v = acc[i][j][r] + bias[(row & 31) * 1024 + col];
          Cf[(size_t)row * 1024 + col] = fmaxf(v, 0.f);
        } else {
          Cb[(size_t)row * 1024 + col] = __float2bfloat16(acc[i][j][r]);
        }
      }
    }
  }
}

extern "C" void kernel_launch(void* const* d_in, const int* in_sizes, int n_in,
                              void* d_out, int out_size, void* d_ws, size_t ws_size,
                              hipStream_t stream) {
  const float* x     = (const float*)d_in[0];   // (256, 32768) fp32
  const float* nodes = (const float*)d_in[1];   // (6, 32,32,32,32) fp32
  const float* bias  = (const float*)d_in[2];   // (32768,) fp32
  float* out = (float*)d_out;                   // (256, 32768) fp32

  // ws layout: buf0 16MB | buf1 16MB | nodeT 12MB  => 44MB needed
  bf16* buf0  = (bf16*)d_ws;
  bf16* buf1  = buf0 + (size_t)BATCH * DL3;
  bf16* nodeT = buf1 + (size_t)BATCH * DL3;

  prep_x<<<dim3(BATCH * 32), dim3(256), 0, stream>>>(x, buf0);
  prep_nodes<<<dim3(6 * 1024), dim3(256), 0, stream>>>(nodes, nodeT);

  dim3 grid(64, 8), blk(256);
  entangler_gemm<false><<<grid, blk, 0, stream>>>(buf0, nodeT + (size_t)0 * 1048576, buf1, nullptr, nullptr);
  entangler_gemm<false><<<grid, blk, 0, stream>>>(buf1, nodeT + (size_t)1 * 1048576, buf0, nullptr, nullptr);
  entangler_gemm<false><<<grid, blk, 0, stream>>>(buf0, nodeT + (size_t)2 * 1048576, buf1, nullptr, nullptr);
  entangler_gemm<false><<<grid, blk, 0, stream>>>(buf1, nodeT + (size_t)3 * 1048576, buf0, nullptr, nullptr);
  entangler_gemm<false><<<grid, blk, 0, stream>>>(buf0, nodeT + (size_t)4 * 1048576, buf1, nullptr, nullptr);
  entangler_gemm<true ><<<grid, blk, 0, stream>>>(buf1, nodeT + (size_t)5 * 1048576, nullptr, out, bias);
}

// Round 2
// 231.212 us; speedup vs baseline: 1.0087x; 1.0006x over previous
//
#include <hip/hip_runtime.h>
#include <hip/hip_bf16.h>
#include <stdint.h>

using bf16 = __hip_bfloat16;
typedef __attribute__((ext_vector_type(8))) short short8;
typedef __attribute__((ext_vector_type(4))) float floatx4;

#define DD 32
#define DL3 32768      // 32^3
#define BATCH 256
#define NK 1024        // 32*32

// GEMM tile geometry: 256x128 block, BK=64 (2 kk-chunks of 32), 8 waves = 2M x 2N x 2K
#define BM 256
#define BN 128
#define NKT 16                 // K-tiles of 64 in K=1024
#define A_ELEM 16384           // A region per buffer: 256*64 bf16 = 32KB
#define B_ELEM 8192            // B region per buffer: 128*64 bf16 = 16KB
#define BUF_ELEM 24576         // 48KB per buffer (bf16 elems)
#define LDS_BYTES 147456       // 3 buffers * 48KB

// async global->LDS, 16B per lane (wave-uniform base + lane*16 layout respected)
__device__ __forceinline__ void load16(const void* g, void* l) {
  __builtin_amdgcn_global_load_lds((const __attribute__((address_space(1))) void*)g,
                                   (__attribute__((address_space(3))) void*)l,
                                   16, 0, 0);
}

// dst[b][v][f][u] = x[b][u][v][f]  (fp32 -> bf16)
__global__ __launch_bounds__(256) void prep_x(const float* __restrict__ x, bf16* __restrict__ dst) {
  int b = blockIdx.x >> 5, v = blockIdx.x & 31;
  __shared__ float tile[32][33];
  const float* xb = x + (size_t)b * DL3 + v * DD;
  int t = threadIdx.x;
#pragma unroll
  for (int it = 0; it < 4; ++it) {
    int u = (t >> 5) + it * 8, f = t & 31;
    tile[u][f] = xb[u * NK + f];
  }
  __syncthreads();
  bf16* db = dst + (size_t)b * DL3 + v * NK;
#pragma unroll
  for (int it = 0; it < 4; ++it) {
    int f = (t >> 5) + it * 8, u = t & 31;
    db[f * DD + u] = __float2bfloat16(tile[u][f]);
  }
}

// nodeT[i][n][v*32+u] = node[i][u*32+v][n]  (fp32 -> bf16)
__global__ __launch_bounds__(256) void prep_nodes(const float* __restrict__ nodes, bf16* __restrict__ dst) {
  int id = blockIdx.x;
  int nb = id & 31, kb = (id >> 5) & 31, i = id >> 10;
  const float* src = nodes + (size_t)i * 1048576;
  bf16* d = dst + (size_t)i * 1048576;
  __shared__ float tile[32][33];
  int t = threadIdx.x;
#pragma unroll
  for (int it = 0; it < 4; ++it) {
    int u = (t >> 5) + it * 8, j = t & 31;
    tile[u][j] = src[(size_t)(u * 32 + kb) * 1024 + nb * 32 + j];
  }
  __syncthreads();
#pragma unroll
  for (int it = 0; it < 4; ++it) {
    int j = (t >> 5) + it * 8, u = t & 31;
    d[(size_t)(nb * 32 + j) * 1024 + kb * 32 + u] = __float2bfloat16(tile[u][j]);
  }
}

// C[(b*32+f)][n] = sum_k A[(b,f)][k] * Bt[k][n]
//   A[(b,f)][(v*32+u)] = Asrc[b*32768 + v*1024 + f*32 + u]
//   Bt[k][n] = nodeT[n][k]
// 256x128 tile, 8 waves = 2M x 2N x 2K (wave tile 128x64, each wave does one
// kk-half of every K-tile; wave pairs reduce through LDS at the end).
// 3-deep LDS pipeline with counted vmcnt(6) (T4), raw s_barrier, T2 XOR-swizzle
// (byte ^= ((byte>>7)&3)<<4, both-sides: pre-swizzled global source + swizzled
// ds_read addr), setprio around MFMA cluster (T5).
template <bool FINAL>
__global__ __launch_bounds__(512, 2) void entangler_gemm(
    const bf16* __restrict__ A, const bf16* __restrict__ Bn,
    bf16* __restrict__ Cb, float* __restrict__ Cf, const float* __restrict__ bias) {
  extern __shared__ char smem[];
  bf16* lds = (bf16*)smem;

  const int t = threadIdx.x;
  const int lane = t & 63;
  const int lane16 = lane & 15, quad = lane >> 4;
  const int w = t >> 6;
  const int wm = (w >> 2) & 1, wn = (w >> 1) & 1, wk = w & 1;
  const int sel = (lane16 >> 1) & 3;          // swizzle selector (addr bits 7-8)
  const int qs = (quad ^ sel) * 8;            // swizzled quad offset, bf16 elems
  const int b0 = blockIdx.x * 8;              // 8 batch elems per 256-row tile
  const int N0 = blockIdx.y * 128;

  // read-side element offsets within a buffer (kk = wk fixed per wave)
  const int aRd = wk * 8192 + (wm * 128 + lane16) * 32 + qs;
  const int bRd = A_ELEM + wk * 4096 + (wn * 64 + lane16) * 32 + qs;

  // stage-side: physical LDS slot P (linear, global_load_lds writes base+lane*16),
  // logical slot L = P ^ swz (involution); decode L -> global source address.
  int aOff[4], aLds[4], bOff[2], bLds[2];
#pragma unroll
  for (int r = 0; r < 4; ++r) {
    int P = (r * 512 + t) * 16;               // byte offset in A region
    int L = P ^ (((P >> 7) & 3) << 4);
    int kk = L >> 14, m = (L >> 6) & 255, u0 = (L & 63) >> 1;
    aOff[r] = (b0 + (m >> 5)) * DL3 + kk * NK + (m & 31) * 32 + u0;
    aLds[r] = P >> 1;
  }
#pragma unroll
  for (int r = 0; r < 2; ++r) {
    int P = (r * 512 + t) * 16;               // byte offset in B region
    int L = P ^ (((P >> 7) & 3) << 4);
    int kk = L >> 13, n = (L >> 6) & 127, u0 = (L & 63) >> 1;
    bOff[r] = (N0 + n) * NK + kk * 32 + u0;
    bLds[r] = A_ELEM + (P >> 1);
  }

  floatx4 acc[8][4];
#pragma unroll
  for (int i = 0; i < 8; ++i)
#pragma unroll
    for (int j = 0; j < 4; ++j)
      acc[i][j] = (floatx4){0.f, 0.f, 0.f, 0.f};

  // Prologue: stage K-tiles 0 and 1 into buffers 0 and 1 (12 loads in flight).
#pragma unroll
  for (int s = 0; s < 2; ++s) {
    bf16* bp = lds + s * BUF_ELEM;
#pragma unroll
    for (int r = 0; r < 4; ++r) load16(A + aOff[r] + s * 2048, bp + aLds[r]);
#pragma unroll
    for (int r = 0; r < 2; ++r) load16(Bn + bOff[r] + s * 64, bp + bLds[r]);
  }
  asm volatile("s_waitcnt vmcnt(6)" ::: "memory");  // tile 0 landed (per wave)
  __builtin_amdgcn_s_barrier();                      // all waves' tile 0 visible
  asm volatile("" ::: "memory");

#pragma unroll
  for (int kt = 0; kt < NKT; ++kt) {
    const bf16* bp = lds + (kt % 3) * BUF_ELEM;
    // ds_read this wave's kk-half fragments (12 x b128, conflict-free swizzled)
    short8 af[8], bfr[4];
#pragma unroll
    for (int i = 0; i < 8; ++i) af[i] = *(const short8*)(bp + aRd + i * 512);
#pragma unroll
    for (int j = 0; j < 4; ++j) bfr[j] = *(const short8*)(bp + bRd + j * 512);
    // issue stage(kt+2) into buf[(kt+2)%3] (that buffer's readers finished at
    // the barrier closing iter kt-1)
    if (kt < NKT - 2) {
      bf16* np = lds + ((kt + 2) % 3) * BUF_ELEM;
#pragma unroll
      for (int r = 0; r < 4; ++r) load16(A + aOff[r] + (kt + 2) * 2048, np + aLds[r]);
#pragma unroll
      for (int r = 0; r < 2; ++r) load16(Bn + bOff[r] + (kt + 2) * 64, np + bLds[r]);
    }
    asm volatile("" ::: "memory");
    __builtin_amdgcn_s_barrier();               // B1: align wave phases
    asm volatile("" ::: "memory");
    __builtin_amdgcn_s_setprio(1);
#pragma unroll
    for (int i = 0; i < 8; ++i)
#pragma unroll
      for (int j = 0; j < 4; ++j)
        acc[i][j] = __builtin_amdgcn_mfma_f32_16x16x32_bf16(af[i], bfr[j], acc[i][j], 0, 0, 0);
    __builtin_amdgcn_s_setprio(0);
    // counted vmcnt: leave stage(kt+2)'s 6 loads in flight, wait only stage(kt+1)
    if (kt < NKT - 2) {
      asm volatile("s_waitcnt vmcnt(6)" ::: "memory");
    } else if (kt == NKT - 2) {
      asm volatile("s_waitcnt vmcnt(0)" ::: "memory");   // last tile (15) landed
    }
    if (kt < NKT - 1) {
      __builtin_amdgcn_s_barrier();             // B2: publish tile kt+1 + read-done
      asm volatile("" ::: "memory");
    }
  }

  // Cross-wave K-reduction: wk=1 waves dump acc to LDS, wk=0 waves add + write C.
  __syncthreads();   // safe: vmcnt fully drained (kt=14 waited vmcnt(0))
  float* red = (float*)smem;
  const int pair = (wm << 1) | wn;
  if (wk == 1) {
    float* dst = red + pair * 8192;
#pragma unroll
    for (int i = 0; i < 8; ++i)
#pragma unroll
      for (int j = 0; j < 4; ++j)
        *(floatx4*)(dst + ((i * 4 + j) * 64 + lane) * 4) = acc[i][j];
  }
  __syncthreads();
  if (wk == 0) {
    const float* src = red + pair * 8192;
    const int R0 = blockIdx.x * 256;
#pragma unroll
    for (int i = 0; i < 8; ++i) {
#pragma unroll
      for (int j = 0; j < 4; ++j) {
        floatx4 p = *(const floatx4*)(src + ((i * 4 + j) * 64 + lane) * 4);
        acc[i][j] += p;
#pragma unroll
        for (int r = 0; r < 4; ++r) {
          // C/D layout: col = lane&15, row = quad*4 + reg  [m89-verified]
          int row = R0 + wm * 128 + i * 16 + quad * 4 + r;
          int col = N0 + wn * 64 + j * 16 + lane16;
          if (FINAL) {
            float v = acc[i][j][r] + bias[(row & 31) * 1024 + col];
            Cf[(size_t)row * 1024 + col] = fmaxf(v, 0.f);
          } else {
            Cb[(size_t)row * 1024 + col] = __float2bfloat16(acc[i][j][r]);
          }
        }
      }
    }
  }
}

extern "C" void kernel_launch(void* const* d_in, const int* in_sizes, int n_in,
                              void* d_out, int out_size, void* d_ws, size_t ws_size,
                              hipStream_t stream) {
  const float* x     = (const float*)d_in[0];   // (256, 32768) fp32
  const float* nodes = (const float*)d_in[1];   // (6, 32,32,32,32) fp32
  const float* bias  = (const float*)d_in[2];   // (32768,) fp32
  float* out = (float*)d_out;                   // (256, 32768) fp32

  // ws layout: buf0 16MB | buf1 16MB | nodeT 12MB  => 44MB needed
  bf16* buf0  = (bf16*)d_ws;
  bf16* buf1  = buf0 + (size_t)BATCH * DL3;
  bf16* nodeT = buf1 + (size_t)BATCH * DL3;

  // opt-in to >64KB dynamic LDS (host-side, immediate; graph-capture safe)
  static bool attr_done = false;
  if (!attr_done) {
    hipFuncSetAttribute((const void*)entangler_gemm<false>,
                        hipFuncAttributeMaxDynamicSharedMemorySize, LDS_BYTES);
    hipFuncSetAttribute((const void*)entangler_gemm<true>,
                        hipFuncAttributeMaxDynamicSharedMemorySize, LDS_BYTES);
    attr_done = true;
  }

  prep_x<<<dim3(BATCH * 32), dim3(256), 0, stream>>>(x, buf0);
  prep_nodes<<<dim3(6 * 1024), dim3(256), 0, stream>>>(nodes, nodeT);

  dim3 grid(32, 8), blk(512);
  entangler_gemm<false><<<grid, blk, LDS_BYTES, stream>>>(buf0, nodeT + (size_t)0 * 1048576, buf1, nullptr, nullptr);
  entangler_gemm<false><<<grid, blk, LDS_BYTES, stream>>>(buf1, nodeT + (size_t)1 * 1048576, buf0, nullptr, nullptr);
  entangler_gemm<false><<<grid, blk, LDS_BYTES, stream>>>(buf0, nodeT + (size_t)2 * 1048576, buf1, nullptr, nullptr);
  entangler_gemm<false><<<grid, blk, LDS_BYTES, stream>>>(buf1, nodeT + (size_t)3 * 1048576, buf0, nullptr, nullptr);
  entangler_gemm<false><<<grid, blk, LDS_BYTES, stream>>>(buf0, nodeT + (size_t)4 * 1048576, buf1, nullptr, nullptr);
  entangler_gemm<true ><<<grid, blk, LDS_BYTES, stream>>>(buf1, nodeT + (size_t)5 * 1048576, nullptr, out, bias);
}